// Round 7
// baseline (333.272 us; speedup 1.0000x reference)
//
#include <hip/hip_runtime.h>

// NormalizationLayer: out = (v, exp(-adj^2 * c)), c = 1/(2*(100*sigmoid(s)+1e-5)^2),
// s = (v W1^T)(v W2^T)^T = v (W1^T W2) v^T = (v M) v^T.
//
// R11 = UNFUSE the epilogue. R6-R10 post-mortems: the fused gemm<1> is stuck
// at ~87us / 41% HBM duty because per-CU its HBM activity is bursts separated
// by barrier-locked GEMM phases; three overlap schemes (reg prefetch, persistence,
// XCD swizzle) all failed to beat it. Meanwhile harness fills prove 83% duty
// for barrier-free streams. p(f16) is only 64 MiB -> fits L3, so the round
// trip is cheap:
//   - gemm<1> now writes p = 100*sigmoid(s)+1e-5 (f16) to workspace (mostly
//     L3-resident), back at launch_bounds(256,4), no adj anywhere.
//   - new stream_kernel: pure grid-stride stream out = exp(-0.5*(adj/p)^2):
//     NT-load adj + NT-store out (protect p's L3 residency), plain-load p.
//     No LDS, no barriers, 32 waves/CU -> fill-like duty expected.

typedef _Float16 half8_t __attribute__((ext_vector_type(8)));
typedef _Float16 half4_t __attribute__((ext_vector_type(4)));
typedef float floatx4 __attribute__((ext_vector_type(4)));

#define LDSS 72   // K-loop LDS row stride in f16 (144 B, b128-aligned)
#define PS   132  // p-tile row stride in f16 (264 B, banks balanced)

// ---------------- kernel 1: copy v -> out0, convert v -> f16 ----------------
__global__ void prep_kernel(const floatx4* __restrict__ v4,
                            floatx4* __restrict__ out4,
                            half4_t* __restrict__ vf4) {
    int idx = blockIdx.x * 256 + threadIdx.x;   // 4096*256 = 4194304/4 exact
    floatx4 t = v4[idx];
    out4[idx] = t;
    half4_t h;
    h[0] = (_Float16)t[0]; h[1] = (_Float16)t[1];
    h[2] = (_Float16)t[2]; h[3] = (_Float16)t[3];
    vf4[idx] = h;
}

// ---------------- kernel 2: Mt[j][i] = sum_o W2[o][j] * W1[o][i] ----------------
__global__ void mt_kernel(const float* __restrict__ W1,
                          const float* __restrict__ W2,
                          _Float16* __restrict__ Mt) {
    __shared__ float w2col[256];
    const int j = blockIdx.x;
    const int i = threadIdx.x;
    w2col[i] = W2[i * 256 + j];
    __syncthreads();
    float acc = 0.f;
    #pragma unroll 8
    for (int o = 0; o < 256; ++o)
        acc += w2col[o] * W1[o * 256 + i];
    Mt[j * 256 + i] = (_Float16)acc;
}

// ---------------- GEMM: C[m][n] = sum_k A[m,k]*Bm[n,k], K=256, tile 128x128 ----
// MFMA operand roles: A-op = n-frag, B-op = m-frag => D: n = quad*4+reg, m = l16.
// MODE 0: store half4 u-tile (Out row stride 256, grid.y = n-tile).
// MODE 1: p = 100*sigmoid(s)+1e-5 -> f16 via LDS transform -> coalesced store
//         to Out (row stride 2048, batch offset from blockIdx.z).
template<int MODE>
__global__ __launch_bounds__(256, 4)
void gemm_kernel(const _Float16* __restrict__ A, const _Float16* __restrict__ Bm,
                 size_t a_bstride, size_t b_bstride,
                 _Float16* __restrict__ Out) {
    __shared__ _Float16 smem[2 * 128 * LDSS];   // As | Bs ; reused as p-tile (128*PS)
    _Float16* As = smem;
    _Float16* Bs = smem + 128 * LDSS;

    const int tid  = threadIdx.x;
    const int lane = tid & 63;
    const int wid  = tid >> 6;
    const int wm   = wid >> 1;          // 2x2 wave grid, each wave 64(m)x64(n)
    const int wn   = wid & 1;
    const int quad = lane >> 4;
    const int l16  = lane & 15;
    const int rrow = tid >> 3;          // staging: 8 threads (8x16B) per 64-col row
    const int ch8  = (tid & 7) * 8;

    const int m0 = blockIdx.x * 128;
    const int n0 = blockIdx.y * 128;
    const int batch = blockIdx.z;

    const _Float16* Ab = A  + (size_t)batch * a_bstride;
    const _Float16* Bb = Bm + (size_t)batch * b_bstride;

    floatx4 acc[4][4];   // acc[i][j]: i -> n-frag, j -> m-frag
    #pragma unroll
    for (int i = 0; i < 4; ++i)
        #pragma unroll
        for (int j = 0; j < 4; ++j)
            acc[i][j] = (floatx4){0.f, 0.f, 0.f, 0.f};

    #pragma unroll
    for (int kc = 0; kc < 256; kc += 64) {
        if (kc) __syncthreads();        // iter-0 barrier elided (LDS not yet read)
        #pragma unroll
        for (int r = 0; r < 4; ++r) {
            int row = r * 32 + rrow;
            uint4 va = *(const uint4*)(Ab + (((size_t)(m0 + row)) << 8) + kc + ch8);
            uint4 vb = *(const uint4*)(Bb + (((size_t)(n0 + row)) << 8) + kc + ch8);
            *(uint4*)(&As[row * LDSS + ch8]) = va;
            *(uint4*)(&Bs[row * LDSS + ch8]) = vb;
        }
        __syncthreads();
        #pragma unroll
        for (int ks = 0; ks < 2; ++ks) {
            const int kof = ks * 32 + quad * 8;   // operand layout: [row=lane&15][k=quad*8+j]
            half8_t mf[4], nf[4];
            #pragma unroll
            for (int t = 0; t < 4; ++t) {
                mf[t] = *(const half8_t*)(&As[(wm * 64 + t * 16 + l16) * LDSS + kof]);
                nf[t] = *(const half8_t*)(&Bs[(wn * 64 + t * 16 + l16) * LDSS + kof]);
            }
            #pragma unroll
            for (int i = 0; i < 4; ++i)
                #pragma unroll
                for (int j = 0; j < 4; ++j)
                    acc[i][j] = __builtin_amdgcn_mfma_f32_16x16x32_f16(
                        nf[i], mf[j], acc[i][j], 0, 0, 0);   // A-op = n, B-op = m
        }
    }

    if (MODE == 0) {
        // D layout: n = quad*4 + reg, m = l16
        #pragma unroll
        for (int j = 0; j < 4; ++j) {
            int m = m0 + wm * 64 + j * 16 + l16;        // u row
            #pragma unroll
            for (int i = 0; i < 4; ++i) {
                int n = wn * 64 + i * 16 + quad * 4;    // u col (grid.y covers n0)
                half4_t h;
                #pragma unroll
                for (int r = 0; r < 4; ++r) h[r] = (_Float16)acc[i][j][r];
                *(half4_t*)(Out + (size_t)m * 256 + n0 + n) = h;
            }
        }
    } else {
        // Phase 1: p = 100*sigmoid(s) + 1e-5 -> f16 LDS tile (layout transform)
        __syncthreads();                      // all waves done reading As/Bs
        _Float16* Ps = smem;                  // 128 * PS * 2 = 33792 B <= 36864 B
        #pragma unroll
        for (int j = 0; j < 4; ++j) {
            int ml = wm * 64 + j * 16 + l16;
            #pragma unroll
            for (int i = 0; i < 4; ++i) {
                int nl = wn * 64 + i * 16 + quad * 4;
                half4_t h;
                #pragma unroll
                for (int r = 0; r < 4; ++r) {
                    float s = acc[i][j][r];
                    float p = 100.0f / (1.0f + __expf(-s)) + 1e-5f;
                    h[r] = (_Float16)p;
                }
                *(half4_t*)(&Ps[ml * PS + nl]) = h;
            }
        }
        __syncthreads();

        // Phase 2: coalesced p store (256 B contiguous per row per pass).
        // Normal (temporal) stores: p should stay L3-resident for stream_kernel.
        _Float16* Pb = Out + (size_t)batch * 2048 * 2048;
        const int srow = tid >> 5;            // 0..7
        const int scol = (tid & 31) * 4;
        #pragma unroll 4
        for (int pass = 0; pass < 16; ++pass) {
            int r = pass * 8 + srow;
            half4_t ph = *(const half4_t*)(&Ps[r * PS + scol]);
            *(half4_t*)(Pb + (size_t)(m0 + r) * 2048 + n0 + scol) = ph;
        }
    }
}

// ---------------- kernel 4: pure stream, out = exp(-0.5*(adj/p)^2) ----------
// Barrier-free, LDS-free, grid-stride: the fill-duty regime (~83% HBM).
// NT on adj/out (one-shot streams) protects p's L3 residency.
__global__ __launch_bounds__(256)
void stream_kernel(const floatx4* __restrict__ adj4,
                   const half4_t* __restrict__ p4,
                   floatx4* __restrict__ out4) {
    const size_t base = (size_t)blockIdx.x * 256 + threadIdx.x;
    const size_t stride = (size_t)2048 * 256;      // total threads
    #pragma unroll 4
    for (int it = 0; it < 16; ++it) {              // 16 * 524288 = 8388608 chunks exact
        size_t g = base + (size_t)it * stride;
        floatx4 a = __builtin_nontemporal_load(adj4 + g);
        half4_t ph = p4[g];
        floatx4 o;
        #pragma unroll
        for (int e = 0; e < 4; ++e) {
            float ip = __builtin_amdgcn_rcpf((float)ph[e]);
            float q = a[e] * ip;
            o[e] = __expf(-0.5f * q * q);
        }
        __builtin_nontemporal_store(o, out4 + g);
    }
}

extern "C" void kernel_launch(void* const* d_in, const int* in_sizes, int n_in,
                              void* d_out, int out_size, void* d_ws, size_t ws_size,
                              hipStream_t stream) {
    const float* v   = (const float*)d_in[0];   // [8,2048,256]
    const float* adj = (const float*)d_in[1];   // [8,2048,2048]
    const float* W1  = (const float*)d_in[2];   // [256,256]
    const float* W2  = (const float*)d_in[3];   // [256,256]

    float* out_v   = (float*)d_out;                              // output 0: v copy
    float* out_adj = (float*)d_out + (size_t)8 * 2048 * 256;     // output 1

    char* ws = (char*)d_ws;
    _Float16* vf = (_Float16*)ws;                          // 8 MiB   [8*2048,256] f16
    _Float16* uf = (_Float16*)(ws + ((size_t)8 << 20));    // 8 MiB   [8*2048,256] f16
    _Float16* Mt = (_Float16*)(ws + ((size_t)16 << 20));   // 128 KiB [256,256] f16 (M^T)
    _Float16* pf = (_Float16*)(ws + ((size_t)17 << 20));   // 64 MiB  [8,2048,2048] f16

    prep_kernel<<<4096, 256, 0, stream>>>((const floatx4*)v, (floatx4*)out_v, (half4_t*)vf);
    mt_kernel<<<256, 256, 0, stream>>>(W1, W2, Mt);
    // u = v * M : A rows = 16384 (all batches flat), Bm = Mt (256 rows)
    gemm_kernel<0><<<dim3(128, 2, 1), 256, 0, stream>>>(
        vf, Mt, 0, 0, uf);
    // p = 100*sigmoid(u v^T) + 1e-5, per batch, f16 -> workspace (L3-resident)
    gemm_kernel<1><<<dim3(16, 16, 8), 256, 0, stream>>>(
        uf, vf, (size_t)2048 * 256, (size_t)2048 * 256, pf);
    // out = exp(-0.5*(adj/p)^2), pure stream
    stream_kernel<<<2048, 256, 0, stream>>>(
        (const floatx4*)adj, (const half4_t*)pf, (floatx4*)out_adj);
}

// Round 8
// 295.648 us; speedup vs baseline: 1.1273x; 1.1273x over previous
//
#include <hip/hip_runtime.h>

// NormalizationLayer: out = (v, exp(-adj^2 * c)), c = 1/(2*(100*sigmoid(s)+1e-5)^2),
// s = (v W1^T)(v W2^T)^T = v (W1^T W2) v^T = (v M) v^T.
//
// R12 = R6 structure (fused epilogue, launch_bounds(256,3), aj0 32-VGPR entry
// prefetch, aj1 mid-kernel; R11's unfuse regressed +18us: p evicted from L3
// by the adj/out streams) + async K-loop staging:
//   - global_load_lds (16B/lane, 1KB/wave-instr) replaces global->VGPR->
//     ds_write. Removes the two dependent waitcnt chains per wave per K-step
//     and frees the 32 staging VGPRs (guide Common-mistake #1; m97: +67%).
//   - global_load_lds writes LDS linearly -> LDSS=64 (128B rows). That alone
//     is a 16-way read conflict, so (T2, rule 21 both-sides-or-neither):
//     LDS stays linear, the GLOBAL source is pre-swizzled per lane
//     (slot = (l&7) ^ (l>>3)), and fragment reads apply the same XOR
//     (slot = (ks*4+quad) ^ (l16&7)). 16 lanes -> 8 slots = 2-way = free.
//   - smem shrinks to 33792 B (Ps 128x132 still fits; As+Bs = 32KB).

typedef _Float16 half8_t __attribute__((ext_vector_type(8)));
typedef _Float16 half4_t __attribute__((ext_vector_type(4)));
typedef float floatx4 __attribute__((ext_vector_type(4)));

using f16_lds = __attribute__((address_space(3))) _Float16;
using f16_glb = __attribute__((address_space(1))) const _Float16;

#define PS 132  // p-tile row stride in f16 (264 B, banks balanced)

// ---------------- kernel 1: copy v -> out0, convert v -> f16 ----------------
__global__ void prep_kernel(const floatx4* __restrict__ v4,
                            floatx4* __restrict__ out4,
                            half4_t* __restrict__ vf4) {
    int idx = blockIdx.x * 256 + threadIdx.x;   // 4096*256 = 4194304/4 exact
    floatx4 t = v4[idx];
    out4[idx] = t;
    half4_t h;
    h[0] = (_Float16)t[0]; h[1] = (_Float16)t[1];
    h[2] = (_Float16)t[2]; h[3] = (_Float16)t[3];
    vf4[idx] = h;
}

// ---------------- kernel 2: Mt[j][i] = sum_o W2[o][j] * W1[o][i] ----------------
__global__ void mt_kernel(const float* __restrict__ W1,
                          const float* __restrict__ W2,
                          _Float16* __restrict__ Mt) {
    __shared__ float w2col[256];
    const int j = blockIdx.x;
    const int i = threadIdx.x;
    w2col[i] = W2[i * 256 + j];
    __syncthreads();
    float acc = 0.f;
    #pragma unroll 8
    for (int o = 0; o < 256; ++o)
        acc += w2col[o] * W1[o * 256 + i];
    Mt[j * 256 + i] = (_Float16)acc;
}

// ---------------- GEMM: C[m][n] = sum_k A[m,k]*Bm[n,k], K=256, tile 128x128 ----
// MFMA operand roles: A-op = n-frag, B-op = m-frag => D: n = quad*4+reg, m = l16.
// LDS: linear [128][64] f16 per operand (global_load_lds dest), XOR-swizzled
// contents: physical 16B-slot p holds logical slot p^(row&7).
// MODE 0: store half4 u-tile. MODE 1: p -> LDS, then coalesced streaming epilogue.
template<int MODE>
__global__ __launch_bounds__(256, 3)
void gemm_kernel(const _Float16* __restrict__ A, const _Float16* __restrict__ Bm,
                 size_t a_bstride, size_t b_bstride,
                 _Float16* __restrict__ Uout,
                 const float* __restrict__ adj, float* __restrict__ out) {
    __shared__ _Float16 smem[16896];           // As(8192) | Bs(8192); Ps = 128*132
    _Float16* As = smem;
    _Float16* Bs = smem + 8192;

    const int tid  = threadIdx.x;
    const int lane = tid & 63;
    const int wid  = tid >> 6;
    const int wm   = wid >> 1;          // 2x2 wave grid, each wave 64(m)x64(n)
    const int wn   = wid & 1;
    const int quad = lane >> 4;
    const int l16  = lane & 15;

    // staging geometry: chunk = wid*4+q covers rows chunk*8..+7 (1 KB of LDS);
    // lane l -> row chunk*8 + (l>>3), physical slot l&7, logical slot (l&7)^(l>>3)
    const int lr  = lane >> 3;          // 0..7
    const int lcs = (lane & 7) ^ lr;    // logical 16B slot this lane must fetch

    const int m0 = blockIdx.x * 128;
    const int n0 = blockIdx.y * 128;
    const int batch = blockIdx.z;

    const _Float16* Ab = A  + (size_t)batch * a_bstride;
    const _Float16* Bb = Bm + (size_t)batch * b_bstride;

    // ---- epilogue addressing + adj prefetch (MODE 1) ----
    const int srow = tid >> 5;            // 0..7
    const int scol = (tid & 31) * 4;
    const size_t gbase = (size_t)batch * 2048 * 2048
                       + (size_t)m0 * 2048 + n0 + scol;

    floatx4 aj0[8];
    if (MODE == 1) {
        // First half of this block's adj tile in flight during the K-loop.
        // (R5/R8/R9 lesson: 32 prefetch VGPRs is the no-spill budget here.)
        #pragma unroll
        for (int p = 0; p < 8; ++p)
            aj0[p] = __builtin_nontemporal_load(
                (const floatx4*)(adj + gbase + (size_t)(p * 8 + srow) * 2048));
        asm volatile("" ::: "memory");    // pin issue point: no sinking past K-loop
    }

    floatx4 acc[4][4];   // acc[i][j]: i -> n-frag, j -> m-frag
    #pragma unroll
    for (int i = 0; i < 4; ++i)
        #pragma unroll
        for (int j = 0; j < 4; ++j)
            acc[i][j] = (floatx4){0.f, 0.f, 0.f, 0.f};

    #pragma unroll
    for (int kc = 0; kc < 256; kc += 64) {
        if (kc) __syncthreads();        // all waves done reading As/Bs of prev step
        // async staging: 4 A-chunks + 4 B-chunks per wave, 1 KB each,
        // global source pre-swizzled so LDS slot p holds logical slot p^(row&7)
        #pragma unroll
        for (int q = 0; q < 4; ++q) {
            const int chunk = wid * 4 + q;
            const int row = chunk * 8 + lr;
            const _Float16* ga = Ab + (((size_t)(m0 + row)) << 8) + kc + lcs * 8;
            const _Float16* gb = Bb + (((size_t)(n0 + row)) << 8) + kc + lcs * 8;
            __builtin_amdgcn_global_load_lds((f16_glb*)ga, (f16_lds*)(As + chunk * 512),
                                             16, 0, 0);
            __builtin_amdgcn_global_load_lds((f16_glb*)gb, (f16_lds*)(Bs + chunk * 512),
                                             16, 0, 0);
        }
        __syncthreads();                // drains vmcnt -> DMA'd data visible
        #pragma unroll
        for (int ks = 0; ks < 2; ++ks) {
            half8_t mf[4], nf[4];
            const int psl = ((ks * 4 + quad) ^ (l16 & 7)) * 8;  // physical f16 offset
            #pragma unroll
            for (int t = 0; t < 4; ++t) {
                mf[t] = *(const half8_t*)(&As[(wm * 64 + t * 16 + l16) * 64 + psl]);
                nf[t] = *(const half8_t*)(&Bs[(wn * 64 + t * 16 + l16) * 64 + psl]);
            }
            #pragma unroll
            for (int i = 0; i < 4; ++i)
                #pragma unroll
                for (int j = 0; j < 4; ++j)
                    acc[i][j] = __builtin_amdgcn_mfma_f32_16x16x32_f16(
                        nf[i], mf[j], acc[i][j], 0, 0, 0);   // A-op = n, B-op = m
        }
    }

    if (MODE == 0) {
        // D layout: n = quad*4 + reg, m = l16
        #pragma unroll
        for (int j = 0; j < 4; ++j) {
            int m = m0 + wm * 64 + j * 16 + l16;        // u row
            #pragma unroll
            for (int i = 0; i < 4; ++i) {
                int n = wn * 64 + i * 16 + quad * 4;    // u col (grid.y covers n0)
                half4_t h;
                #pragma unroll
                for (int r = 0; r < 4; ++r) h[r] = (_Float16)acc[i][j][r];
                *(half4_t*)(Uout + (size_t)m * 256 + n0 + n) = h;
            }
        }
    } else {
        // Phase 1: p = 100*sigmoid(s) + 1e-5 -> f16 LDS tile (layout transform)
        __syncthreads();                      // all waves done reading As/Bs
        _Float16* Ps = smem;                  // 128 * 132 = 16896 f16 = 33792 B
        #pragma unroll
        for (int j = 0; j < 4; ++j) {
            int ml = wm * 64 + j * 16 + l16;
            #pragma unroll
            for (int i = 0; i < 4; ++i) {
                int nl = wn * 64 + i * 16 + quad * 4;
                half4_t h;
                #pragma unroll
                for (int r = 0; r < 4; ++r) {
                    float s = acc[i][j][r];
                    float p = 100.0f / (1.0f + __expf(-s)) + 1e-5f;
                    h[r] = (_Float16)p;
                }
                *(half4_t*)(&Ps[ml * PS + nl]) = h;
            }
        }

        // Second half of adj tile: acc regs are dead here, fits the budget;
        // latency hides under the barrier + passes 0-7.
        floatx4 aj1[8];
        #pragma unroll
        for (int p = 0; p < 8; ++p)
            aj1[p] = __builtin_nontemporal_load(
                (const floatx4*)(adj + gbase + (size_t)((p + 8) * 8 + srow) * 2048));
        asm volatile("" ::: "memory");

        __syncthreads();

        // Phase 2: fully-coalesced streaming epilogue, all adj already in regs.
        #pragma unroll
        for (int pass = 0; pass < 8; ++pass) {
            int r = pass * 8 + srow;
            size_t g = gbase + (size_t)r * 2048;
            floatx4 a = aj0[pass];
            half4_t ph = *(const half4_t*)(&Ps[r * PS + scol]);
            floatx4 o;
            #pragma unroll
            for (int e = 0; e < 4; ++e) {
                float ip = __builtin_amdgcn_rcpf((float)ph[e]);
                float q = a[e] * ip;
                o[e] = __expf(-0.5f * q * q);
            }
            __builtin_nontemporal_store(o, (floatx4*)(out + g));
        }
        #pragma unroll
        for (int pass = 8; pass < 16; ++pass) {
            int r = pass * 8 + srow;
            size_t g = gbase + (size_t)r * 2048;
            floatx4 a = aj1[pass - 8];
            half4_t ph = *(const half4_t*)(&Ps[r * PS + scol]);
            floatx4 o;
            #pragma unroll
            for (int e = 0; e < 4; ++e) {
                float ip = __builtin_amdgcn_rcpf((float)ph[e]);
                float q = a[e] * ip;
                o[e] = __expf(-0.5f * q * q);
            }
            __builtin_nontemporal_store(o, (floatx4*)(out + g));
        }
    }
}

extern "C" void kernel_launch(void* const* d_in, const int* in_sizes, int n_in,
                              void* d_out, int out_size, void* d_ws, size_t ws_size,
                              hipStream_t stream) {
    const float* v   = (const float*)d_in[0];   // [8,2048,256]
    const float* adj = (const float*)d_in[1];   // [8,2048,2048]
    const float* W1  = (const float*)d_in[2];   // [256,256]
    const float* W2  = (const float*)d_in[3];   // [256,256]

    float* out_v   = (float*)d_out;                              // output 0: v copy
    float* out_adj = (float*)d_out + (size_t)8 * 2048 * 256;     // output 1

    char* ws = (char*)d_ws;
    _Float16* vf = (_Float16*)ws;                          // 8 MiB  [8*2048,256] f16
    _Float16* uf = (_Float16*)(ws + ((size_t)8 << 20));    // 8 MiB  [8*2048,256] f16
    _Float16* Mt = (_Float16*)(ws + ((size_t)16 << 20));   // 128 KiB [256,256] f16 (M^T)

    prep_kernel<<<4096, 256, 0, stream>>>((const floatx4*)v, (floatx4*)out_v, (half4_t*)vf);
    mt_kernel<<<256, 256, 0, stream>>>(W1, W2, Mt);
    // u = v * M : A rows = 16384 (all batches flat), Bm = Mt (256 rows)
    gemm_kernel<0><<<dim3(128, 2, 1), 256, 0, stream>>>(
        vf, Mt, 0, 0, uf, nullptr, nullptr);
    // s = u * v^T per batch + fused epilogue
    gemm_kernel<1><<<dim3(16, 16, 8), 256, 0, stream>>>(
        uf, vf, (size_t)2048 * 256, (size_t)2048 * 256, nullptr, adj, out_adj);
}